// Round 1
// 146.538 us; speedup vs baseline: 1.0260x; 1.0260x over previous
//
#include <hip/hip_runtime.h>
#include <hip/hip_bf16.h>
#include <stdint.h>

#define SEQ   2048
#define DIM   512
#define BATCH 4

typedef __attribute__((ext_vector_type(8))) short  short8;
typedef __attribute__((ext_vector_type(4))) float  floatx4;

static __device__ __forceinline__ unsigned short f2b(float f) {
  return __builtin_bit_cast(unsigned short, __float2bfloat16(f));
}

// async 16B/lane global->LDS (global_load_lds_dwordx4)
static __device__ __forceinline__ void gll16(const void* g, void* l) {
  __builtin_amdgcn_global_load_lds(
      (__attribute__((address_space(1))) void*)(uintptr_t)g,
      (__attribute__((address_space(3))) void*)l, 16, 0, 0);
}

// ---------------------------------------------------------------------------
// Fragment-linear layout (verified): logical [R rows][K] bf16 matrix as 1KB
// fragments of 16 rows x 32 k; frag index = rt*TK + kt; within a frag, lane l
// owns bytes l*16..+15 = MFMA operand row rt*16+(l&15), k octet (l>>4).
// ---------------------------------------------------------------------------

// Pipelined fragment GEMM: 4-slot LDS ring, 3-deep prefetch, counted vmcnt +
// raw s_barrier (loads stay in flight across barriers), setprio around MFMA.
// Correctness: before the barrier that publishes slot kt+1, each wave waits
// vmcnt(2L) -> its own stage(kt+1) loads (oldest L of 3L outstanding) are
// complete; lgkmcnt(0) drains this wave's ds_reads of the slot that the next
// stage() will overwrite. Tail steps lower the count (L, then 0).
// NOTE: no other VMEM ops may occur inside the loop (would break the count).
template <int AF, int BF, int WM, int WN, int KC, int KIT>
__device__ __forceinline__ void fgemm_pipe(
    const char* __restrict__ A, int rtA0, int TKA,
    const char* __restrict__ B, int rtB0, int TKB,
    char* lds, floatx4 (&acc)[AF / WM][BF / WN])
{
  constexpr int AWF  = AF / WM, BWF = BF / WN;
  constexpr int SLOT = (AF + BF) * KC * 1024;
  constexpr int L    = KC * (AF / 8 + BF / 8);   // gll16 per wave per stage
  static_assert(KIT >= 3, "pipeline needs >=3 K-steps");
  const int tid = threadIdx.x;
  const int w = tid >> 6, l = tid & 63;
  const int wm = w % WM, wn = w / WM;

  auto stage = [&](int slot, int kt) {
    char* dst = lds + slot * SLOT;
#pragma unroll
    for (int c = 0; c < KC; ++c) {
#pragma unroll
      for (int q = 0; q < AF / 8; ++q) {
        const int f = q * 8 + w;
        gll16(A + (((size_t)(rtA0 + f) * TKA + kt * KC + c) << 10) + l * 16,
              dst + (c * AF + f) * 1024 + l * 16);
      }
#pragma unroll
      for (int q = 0; q < BF / 8; ++q) {
        const int f = q * 8 + w;
        gll16(B + (((size_t)(rtB0 + f) * TKB + kt * KC + c) << 10) + l * 16,
              dst + (KC * AF + c * BF + f) * 1024 + l * 16);
      }
    }
  };

  // Prologue: 3 slots in flight; publish slot 0 (wait only its L loads).
  stage(0, 0); stage(1, 1); stage(2, 2);
  asm volatile("s_waitcnt vmcnt(%0) lgkmcnt(0)\ns_barrier" :: "n"(2 * L) : "memory");

#pragma unroll 4
  for (int kt = 0; kt < KIT; ++kt) {
    const int cslot = kt & 3;
    if (kt + 3 < KIT) stage((kt + 3) & 3, kt + 3);   // 3-ahead prefetch

    const char* bA = lds + cslot * SLOT;
    const char* bB = bA + KC * AF * 1024;
    short8 af[KC][AWF], bf[KC][BWF];
#pragma unroll
    for (int c = 0; c < KC; ++c) {
#pragma unroll
      for (int i = 0; i < AWF; ++i)
        af[c][i] = *(const short8*)(bA + (c * AF + wm * AWF + i) * 1024 + l * 16);
#pragma unroll
      for (int j = 0; j < BWF; ++j)
        bf[c][j] = *(const short8*)(bB + (c * BF + wn * BWF + j) * 1024 + l * 16);
    }
    __builtin_amdgcn_s_setprio(1);
#pragma unroll
    for (int c = 0; c < KC; ++c)
#pragma unroll
      for (int i = 0; i < AWF; ++i)
#pragma unroll
        for (int j = 0; j < BWF; ++j)
          acc[i][j] = __builtin_amdgcn_mfma_f32_16x16x32_bf16(af[c][i], bf[c][j], acc[i][j], 0, 0, 0);
    __builtin_amdgcn_s_setprio(0);

    if (kt + 1 < KIT) {
      if (kt + 3 < KIT)
        asm volatile("s_waitcnt vmcnt(%0) lgkmcnt(0)\ns_barrier" :: "n"(2 * L) : "memory");
      else if (kt + 2 < KIT)
        asm volatile("s_waitcnt vmcnt(%0) lgkmcnt(0)\ns_barrier" :: "n"(L) : "memory");
      else
        asm volatile("s_waitcnt vmcnt(0) lgkmcnt(0)\ns_barrier" ::: "memory");
    }
  }
}

// ---- K0: setup: X->XbF frags, W->WF frags (transposed), zero rowsum -------
__global__ __launch_bounds__(256) void setup_kernel(
    const float* __restrict__ X, const float* __restrict__ Wq,
    const float* __restrict__ Wk, const float* __restrict__ Wv,
    short8* __restrict__ XbF, short8* __restrict__ WF,
    float* __restrict__ rowsum)
{
  const int flat = blockIdx.x * 256 + threadIdx.x;   // 0..524287
  {
    const int tile = flat >> 6, l = flat & 63;
    const int row = (tile >> 4) * 16 + (l & 15);
    const int k0  = (tile & 15) * 32 + (l >> 4) * 8;
    const float4 v0 = *(const float4*)(X + (size_t)row * DIM + k0);
    const float4 v1 = *(const float4*)(X + (size_t)row * DIM + k0 + 4);
    short8 o;
    o[0] = (short)f2b(v0.x); o[1] = (short)f2b(v0.y);
    o[2] = (short)f2b(v0.z); o[3] = (short)f2b(v0.w);
    o[4] = (short)f2b(v1.x); o[5] = (short)f2b(v1.y);
    o[6] = (short)f2b(v1.z); o[7] = (short)f2b(v1.w);
    XbF[flat] = o;
  }
  if (flat < 3 * 32768) {                            // W -> WF (rows=n, K=k)
    const int z = flat >> 15, within = flat & 32767;
    const float* W = (z == 0) ? Wq : (z == 1) ? Wk : Wv;
    const int tile = within >> 6, l = within & 63;
    const int n  = (tile >> 4) * 16 + (l & 15);
    const int k0 = (tile & 15) * 32 + (l >> 4) * 8;
    short8 o;
#pragma unroll
    for (int e = 0; e < 8; ++e)
      o[e] = (short)f2b(W[(size_t)(k0 + e) * DIM + n]);
    WF[flat] = o;
  }
  if (flat < 2048) ((float4*)rowsum)[flat] = float4{0.f, 0.f, 0.f, 0.f};
}

// ---- K1: QKV. 256x256 tiles. z=0,1: C[d][s] (A=WF, B=XbF) -> QF/KF frags;
//      z=2: C[s][d] (A=XbF, B=WFv) -> VF frags. 8 waves, 192 blocks total. ---
__global__ __launch_bounds__(512, 2) void qkv_kernel(
    const short8* __restrict__ XbF, const short8* __restrict__ WF,
    const float* __restrict__ bq, const float* __restrict__ bk,
    const float* __restrict__ bv,
    unsigned short* __restrict__ QF, unsigned short* __restrict__ KF,
    unsigned short* __restrict__ VF)
{
  __shared__ char lds[131072];   // 4 x 32 KB slots
  const int z = blockIdx.z, job = blockIdx.x;    // 0..63
  const int lane = threadIdx.x & 63, w = threadIdx.x >> 6;
  const int wm = w & 1, wn = w >> 1;             // WM=2, WN=4
  const int x = job & 31, y = job >> 5;          // x: 256-row tile, y: 256-col
  const char* Xc = (const char*)XbF;
  const char* Wc = (const char*)WF;
  floatx4 acc[8][4] = {};

  if (z < 2) {
    fgemm_pipe<16, 16, 2, 4, 1, 16>(Wc + (size_t)z * 524288, y * 16, 16,
                                    Xc, x * 16, 16, lds, acc);
    const float* bias = z ? bk : bq;
    unsigned short* OF = z ? KF : QF;
    const int dbase = y * 256 + wm * 128;
    const int sbase = x * 256 + wn * 64;
#pragma unroll
    for (int i = 0; i < 8; ++i) {
      const int d0 = dbase + i * 16 + (lane >> 4) * 4;
      const float4 b4 = *(const float4*)(bias + d0);
#pragma unroll
      for (int j = 0; j < 4; ++j) {
        const int s = sbase + j * 16 + (lane & 15);
        ushort4 pk;
        pk.x = f2b(acc[i][j][0] + b4.x);
        pk.y = f2b(acc[i][j][1] + b4.y);
        pk.z = f2b(acc[i][j][2] + b4.z);
        pk.w = f2b(acc[i][j][3] + b4.w);
        *(ushort4*)(OF + (size_t)((s >> 4) * 16 + (d0 >> 5)) * 512 +
                    ((((d0 & 31) >> 3) << 4) | (s & 15)) * 8 + (d0 & 7)) = pk;
      }
    }
  } else {
    fgemm_pipe<16, 16, 2, 4, 1, 16>(Xc, x * 16, 16,
                                    Wc + 2 * 524288, y * 16, 16, lds, acc);
    const int sbase = x * 256 + wm * 128;
    const int dbase = y * 256 + wn * 64;
#pragma unroll
    for (int i = 0; i < 8; ++i) {
      const int s0 = sbase + i * 16 + (lane >> 4) * 4;
      const int bt = s0 >> 11, t0 = s0 & 2047;
#pragma unroll
      for (int j = 0; j < 4; ++j) {
        const int d = dbase + j * 16 + (lane & 15);
        const float bn = bv[d];
        ushort4 pk;
        pk.x = f2b(acc[i][j][0] + bn);
        pk.y = f2b(acc[i][j][1] + bn);
        pk.z = f2b(acc[i][j][2] + bn);
        pk.w = f2b(acc[i][j][3] + bn);
        *(ushort4*)(VF + (size_t)bt * DIM * SEQ +
                    (size_t)((d >> 4) * 64 + (t0 >> 5)) * 512 +
                    ((((t0 & 31) >> 3) << 4) | (d & 15)) * 8 + (t0 & 7)) = pk;
      }
    }
  }
}

// ---- K2: S^T = K Q^T, 256t x 256s tiles; exp epilogue -> ScF + rowsum -----
__global__ __launch_bounds__(512, 2) void scores_kernel(
    const unsigned short* __restrict__ QF, const unsigned short* __restrict__ KF,
    unsigned short* __restrict__ ScF, float* __restrict__ rowsum)
{
  __shared__ char lds[131072];   // 4 x 32 KB slots
  const int b = blockIdx.z, x = blockIdx.x, y = blockIdx.y;
  const int lane = threadIdx.x & 63, w = threadIdx.x >> 6;
  const int wm = w & 1, wn = w >> 1;             // WM=2, WN=4
  floatx4 acc[8][4] = {};
  fgemm_pipe<16, 16, 2, 4, 1, 16>((const char*)KF + (size_t)b * 2097152, y * 16, 16,
                                  (const char*)QF + (size_t)b * 2097152, x * 16, 16,
                                  lds, acc);

  unsigned short* S = ScF + (size_t)b * SEQ * SEQ;
  const float scale = 0.044194173824159216f;  // 1/sqrt(512)
  const int tbase = y * 256 + wm * 128;
  const int sbase = x * 256 + wn * 64;
  float colsum[4] = {0.f, 0.f, 0.f, 0.f};
#pragma unroll
  for (int i = 0; i < 8; ++i) {
    const int t0 = tbase + i * 16 + (lane >> 4) * 4;
#pragma unroll
    for (int j = 0; j < 4; ++j) {
      const int s = sbase + j * 16 + (lane & 15);
      float e0 = __expf(acc[i][j][0] * scale);
      float e1 = __expf(acc[i][j][1] * scale);
      float e2 = __expf(acc[i][j][2] * scale);
      float e3 = __expf(acc[i][j][3] * scale);
      colsum[j] += (e0 + e1) + (e2 + e3);
      ushort4 pk;
      pk.x = f2b(e0); pk.y = f2b(e1); pk.z = f2b(e2); pk.w = f2b(e3);
      *(ushort4*)(S + (size_t)((s >> 4) * 64 + (t0 >> 5)) * 512 +
                  ((((t0 & 31) >> 3) << 4) | (s & 15)) * 8 + (t0 & 7)) = pk;
    }
  }
#pragma unroll
  for (int j = 0; j < 4; ++j) {
    colsum[j] += __shfl_xor(colsum[j], 16, 64);
    colsum[j] += __shfl_xor(colsum[j], 32, 64);
  }
  if (lane < 16) {
#pragma unroll
    for (int j = 0; j < 4; ++j)
      atomicAdd(rowsum + b * SEQ + sbase + j * 16 + lane, colsum[j]);
  }
}

// ---- K3: out[s][d] = (ScF . VF) / rowsum[s]; 128x128 tile, BK=64 ----------
__global__ __launch_bounds__(512, 2) void pv_kernel(
    const unsigned short* __restrict__ ScF, const unsigned short* __restrict__ VF,
    const float* __restrict__ rowsum, float* __restrict__ out)
{
  __shared__ char lds[131072];   // 4 x 32 KB slots
  const int b = blockIdx.z, x = blockIdx.x, y = blockIdx.y;
  const int lane = threadIdx.x & 63, w = threadIdx.x >> 6;
  const int wm = w & 1, wn = w >> 1;             // WM=2, WN=4
  floatx4 acc[4][2] = {};
  fgemm_pipe<8, 8, 2, 4, 2, 32>((const char*)ScF + (size_t)b * 8388608, x * 8, 64,
                                (const char*)VF + (size_t)b * 2097152, y * 8, 64,
                                lds, acc);

  const int mbase = x * 128 + wm * 64;
  const int dbase = y * 128 + wn * 32;
#pragma unroll
  for (int i = 0; i < 4; ++i) {
    const int m0 = mbase + i * 16 + (lane >> 4) * 4;
    const float4 rs = *(const float4*)(rowsum + b * SEQ + m0);
    const float inv0 = 1.f / rs.x, inv1 = 1.f / rs.y, inv2 = 1.f / rs.z, inv3 = 1.f / rs.w;
#pragma unroll
    for (int j = 0; j < 2; ++j) {
      const int d = dbase + j * 16 + (lane & 15);
      float* o = out + ((size_t)b * SEQ + m0) * DIM + d;
      o[0 * DIM] = acc[i][j][0] * inv0;
      o[1 * DIM] = acc[i][j][1] * inv1;
      o[2 * DIM] = acc[i][j][2] * inv2;
      o[3 * DIM] = acc[i][j][3] * inv3;
    }
  }
}

extern "C" void kernel_launch(void* const* d_in, const int* in_sizes, int n_in,
                              void* d_out, int out_size, void* d_ws, size_t ws_size,
                              hipStream_t stream) {
  const float* X  = (const float*)d_in[0];
  const float* Wq = (const float*)d_in[1];
  const float* bq = (const float*)d_in[2];
  const float* Wk = (const float*)d_in[3];
  const float* bk = (const float*)d_in[4];
  const float* Wv = (const float*)d_in[5];
  const float* bv = (const float*)d_in[6];
  float* out = (float*)d_out;
  char* ws = (char*)d_ws;

  // workspace layout (bytes)
  short8* XbF = (short8*)(ws + 0);                    //  8 MB   (rows=b*S+s, K=512)
  short8* WF  = (short8*)(ws + 8388608);              //  1.5 MB (rows=n, K=512, x3)
  char*   QF  = ws + 9961472;                         //  8 MB   (rows=s, K=d)
  char*   KF  = ws + 18350080;                        //  8 MB   (rows=s, K=d)
  char*   VF  = ws + 26738688;                        //  8 MB   (rows=d, K=t, per b)
  char*   ScF = ws + 35127296;                        // 32 MB   (rows=s, K=t, per b)
  float*  rowsum = (float*)(ws + 68681728);           // 32 KB

  setup_kernel<<<dim3(2048), 256, 0, stream>>>(X, Wq, Wk, Wv, XbF, WF, rowsum);
  qkv_kernel<<<dim3(64, 1, 3), 512, 0, stream>>>(
      XbF, WF, bq, bk, bv,
      (unsigned short*)QF, (unsigned short*)KF, (unsigned short*)VF);
  scores_kernel<<<dim3(8, 8, 4), 512, 0, stream>>>(
      (const unsigned short*)QF, (const unsigned short*)KF,
      (unsigned short*)ScF, rowsum);
  pv_kernel<<<dim3(16, 4, 4), 512, 0, stream>>>(
      (const unsigned short*)ScF, (const unsigned short*)VF, rowsum, out);
}

// Round 2
// 140.678 us; speedup vs baseline: 1.0688x; 1.0417x over previous
//
#include <hip/hip_runtime.h>
#include <hip/hip_bf16.h>
#include <stdint.h>

#define SEQ   2048
#define DIM   512
#define BATCH 4

typedef __attribute__((ext_vector_type(8))) short  short8;
typedef __attribute__((ext_vector_type(4))) float  floatx4;

static __device__ __forceinline__ unsigned short f2b(float f) {
  return __builtin_bit_cast(unsigned short, __float2bfloat16(f));
}

// async 16B/lane global->LDS (global_load_lds_dwordx4)
static __device__ __forceinline__ void gll16(const void* g, void* l) {
  __builtin_amdgcn_global_load_lds(
      (__attribute__((address_space(1))) void*)(uintptr_t)g,
      (__attribute__((address_space(3))) void*)l, 16, 0, 0);
}

// ---------------------------------------------------------------------------
// Fragment-linear layout (verified): logical [R rows][K] bf16 matrix as 1KB
// fragments of 16 rows x 32 k; frag index = rt*TK + kt; within a frag, lane l
// owns bytes l*16..+15 = MFMA operand row rt*16+(l&15), k octet (l>>4).
// ---------------------------------------------------------------------------

// Phase-interleaved fragment GEMM (m201 8-phase schedule, ported):
//  * 4-slot LDS ring (slot = (AF+BF)*KC KB), 3-deep prefetch.
//  * Each slot split into PH phases: {ds_read A-chunk (+B on phase 0);
//    issue L/PH stage loads; s_barrier; lgkmcnt(0); setprio(1); KC*AC*BWF
//    MFMA; setprio(0); barrier}.  Counted vmcnt(2L) only at the slot's
//    closing barrier (never 0 in steady state); ladder 2L -> L -> 0 at tail.
//  * Correctness: my ds_reads of slot kt are lgkm-retired before kt's closing
//    barrier; other waves' gll16 writes to that ring slot (stage kt+4) are
//    issued only after that barrier. vmcnt(2L) at kt's close retires the
//    oldest L of 3L outstanding = slot kt+1's loads. No other VMEM ops may
//    appear inside the loop (would corrupt the count).
template <int AF, int BF, int WM, int WN, int KC, int PH, int KIT>
__device__ __forceinline__ void fgemm_8p(
    const char* __restrict__ A, int rtA0, int TKA,
    const char* __restrict__ B, int rtB0, int TKB,
    char* lds, floatx4 (&acc)[AF / WM][BF / WN])
{
  constexpr int AWF  = AF / WM, BWF = BF / WN;
  constexpr int SLOT = (AF + BF) * KC * 1024;
  constexpr int L    = KC * (AF / 8 + BF / 8);   // gll16 per wave per slot
  constexpr int AC   = AWF / PH;                 // A-frag rows per phase
  static_assert(KIT >= 3, "pipeline needs >=3 K-slots");
  static_assert(AWF % PH == 0 && L % PH == 0, "phase split must divide");
  const int tid = threadIdx.x;
  const int w = tid >> 6, l = tid & 63;
  const int wm = w % WM, wn = w / WM;

  auto stage_part = [&](int slot, int kt, int p) {
    char* dst = lds + slot * SLOT;
#pragma unroll
    for (int g = p * (L / PH); g < (p + 1) * (L / PH); ++g) {
      if (g < KC * (AF / 8)) {
        const int c = g / (AF / 8), q = g % (AF / 8);
        const int f = q * 8 + w;
        gll16(A + (((size_t)(rtA0 + f) * TKA + kt * KC + c) << 10) + l * 16,
              dst + (c * AF + f) * 1024 + l * 16);
      } else {
        const int h = g - KC * (AF / 8);
        const int c = h / (BF / 8), q = h % (BF / 8);
        const int f = q * 8 + w;
        gll16(B + (((size_t)(rtB0 + f) * TKB + kt * KC + c) << 10) + l * 16,
              dst + (KC * AF + c * BF + f) * 1024 + l * 16);
      }
    }
  };
  auto stage_all = [&](int slot, int kt) {
#pragma unroll
    for (int p = 0; p < PH; ++p) stage_part(slot, kt, p);
  };

  // Prologue: 3 slots in flight; publish slot 0 (wait only its L loads).
  stage_all(0, 0); stage_all(1, 1); stage_all(2, 2);
  asm volatile("s_waitcnt vmcnt(%0) lgkmcnt(0)\ns_barrier" :: "n"(2 * L) : "memory");

  short8 bf[KC][BWF];
#pragma unroll 4
  for (int kt = 0; kt < KIT; ++kt) {
    const char* bA = lds + (kt & 3) * SLOT;
    const char* bB = bA + KC * AF * 1024;
#pragma unroll
    for (int p = 0; p < PH; ++p) {
      short8 af[KC][AC];
#pragma unroll
      for (int c = 0; c < KC; ++c)
#pragma unroll
        for (int i = 0; i < AC; ++i)
          af[c][i] = *(const short8*)(bA + (c * AF + wm * AWF + p * AC + i) * 1024 + l * 16);
      if (p == 0) {
#pragma unroll
        for (int c = 0; c < KC; ++c)
#pragma unroll
          for (int j = 0; j < BWF; ++j)
            bf[c][j] = *(const short8*)(bB + (c * BF + wn * BWF + j) * 1024 + l * 16);
      }
      if (kt + 3 < KIT) stage_part((kt + 3) & 3, kt + 3, p);   // 3-ahead prefetch

      asm volatile("s_barrier" ::: "memory");
      asm volatile("s_waitcnt lgkmcnt(0)" ::: "memory");
      __builtin_amdgcn_s_setprio(1);
#pragma unroll
      for (int c = 0; c < KC; ++c)
#pragma unroll
        for (int i = 0; i < AC; ++i)
#pragma unroll
          for (int j = 0; j < BWF; ++j)
            acc[p * AC + i][j] = __builtin_amdgcn_mfma_f32_16x16x32_bf16(
                af[c][i], bf[c][j], acc[p * AC + i][j], 0, 0, 0);
      __builtin_amdgcn_s_setprio(0);

      if (p == PH - 1) {        // slot-closing barrier: counted vmcnt ladder
        if (kt + 3 < KIT)
          asm volatile("s_waitcnt vmcnt(%0)\ns_barrier" :: "n"(2 * L) : "memory");
        else if (kt + 2 < KIT)
          asm volatile("s_waitcnt vmcnt(%0)\ns_barrier" :: "n"(L) : "memory");
        else if (kt + 1 < KIT)
          asm volatile("s_waitcnt vmcnt(0)\ns_barrier" ::: "memory");
        // last slot: fall through to epilogue, no barrier needed
      } else {
        asm volatile("s_barrier" ::: "memory");
      }
    }
  }
}

// ---- K0: setup: X->XbF frags, W->WF frags (transposed), zero rowsum -------
__global__ __launch_bounds__(256) void setup_kernel(
    const float* __restrict__ X, const float* __restrict__ Wq,
    const float* __restrict__ Wk, const float* __restrict__ Wv,
    short8* __restrict__ XbF, short8* __restrict__ WF,
    float* __restrict__ rowsum)
{
  const int flat = blockIdx.x * 256 + threadIdx.x;   // 0..524287
  {
    const int tile = flat >> 6, l = flat & 63;
    const int row = (tile >> 4) * 16 + (l & 15);
    const int k0  = (tile & 15) * 32 + (l >> 4) * 8;
    const float4 v0 = *(const float4*)(X + (size_t)row * DIM + k0);
    const float4 v1 = *(const float4*)(X + (size_t)row * DIM + k0 + 4);
    short8 o;
    o[0] = (short)f2b(v0.x); o[1] = (short)f2b(v0.y);
    o[2] = (short)f2b(v0.z); o[3] = (short)f2b(v0.w);
    o[4] = (short)f2b(v1.x); o[5] = (short)f2b(v1.y);
    o[6] = (short)f2b(v1.z); o[7] = (short)f2b(v1.w);
    XbF[flat] = o;
  }
  if (flat < 3 * 32768) {                            // W -> WF (rows=n, K=k)
    const int z = flat >> 15, within = flat & 32767;
    const float* W = (z == 0) ? Wq : (z == 1) ? Wk : Wv;
    const int tile = within >> 6, l = within & 63;
    const int n  = (tile >> 4) * 16 + (l & 15);
    const int k0 = (tile & 15) * 32 + (l >> 4) * 8;
    short8 o;
#pragma unroll
    for (int e = 0; e < 8; ++e)
      o[e] = (short)f2b(W[(size_t)(k0 + e) * DIM + n]);
    WF[flat] = o;
  }
  if (flat < 2048) ((float4*)rowsum)[flat] = float4{0.f, 0.f, 0.f, 0.f};
}

// ---- K1: QKV. 256x256 tiles. z=0,1: C[d][s] (A=WF, B=XbF) -> QF/KF frags;
//      z=2: C[s][d] (A=XbF, B=WFv) -> VF frags. 8 waves, 192 blocks total. ---
__global__ __launch_bounds__(512, 2) void qkv_kernel(
    const short8* __restrict__ XbF, const short8* __restrict__ WF,
    const float* __restrict__ bq, const float* __restrict__ bk,
    const float* __restrict__ bv,
    unsigned short* __restrict__ QF, unsigned short* __restrict__ KF,
    unsigned short* __restrict__ VF)
{
  __shared__ char lds[131072];   // 4 x 32 KB slots
  const int z = blockIdx.z, job = blockIdx.x;    // 0..63
  const int lane = threadIdx.x & 63, w = threadIdx.x >> 6;
  const int wm = w & 1, wn = w >> 1;             // WM=2, WN=4
  const int x = job & 31, y = job >> 5;          // x: 256-row tile, y: 256-col
  const char* Xc = (const char*)XbF;
  const char* Wc = (const char*)WF;
  floatx4 acc[8][4] = {};

  if (z < 2) {
    fgemm_8p<16, 16, 2, 4, 1, 2, 16>(Wc + (size_t)z * 524288, y * 16, 16,
                                     Xc, x * 16, 16, lds, acc);
    const float* bias = z ? bk : bq;
    unsigned short* OF = z ? KF : QF;
    const int dbase = y * 256 + wm * 128;
    const int sbase = x * 256 + wn * 64;
#pragma unroll
    for (int i = 0; i < 8; ++i) {
      const int d0 = dbase + i * 16 + (lane >> 4) * 4;
      const float4 b4 = *(const float4*)(bias + d0);
#pragma unroll
      for (int j = 0; j < 4; ++j) {
        const int s = sbase + j * 16 + (lane & 15);
        ushort4 pk;
        pk.x = f2b(acc[i][j][0] + b4.x);
        pk.y = f2b(acc[i][j][1] + b4.y);
        pk.z = f2b(acc[i][j][2] + b4.z);
        pk.w = f2b(acc[i][j][3] + b4.w);
        *(ushort4*)(OF + (size_t)((s >> 4) * 16 + (d0 >> 5)) * 512 +
                    ((((d0 & 31) >> 3) << 4) | (s & 15)) * 8 + (d0 & 7)) = pk;
      }
    }
  } else {
    fgemm_8p<16, 16, 2, 4, 1, 2, 16>(Xc, x * 16, 16,
                                     Wc + 2 * 524288, y * 16, 16, lds, acc);
    const int sbase = x * 256 + wm * 128;
    const int dbase = y * 256 + wn * 64;
#pragma unroll
    for (int i = 0; i < 8; ++i) {
      const int s0 = sbase + i * 16 + (lane >> 4) * 4;
      const int bt = s0 >> 11, t0 = s0 & 2047;
#pragma unroll
      for (int j = 0; j < 4; ++j) {
        const int d = dbase + j * 16 + (lane & 15);
        const float bn = bv[d];
        ushort4 pk;
        pk.x = f2b(acc[i][j][0] + bn);
        pk.y = f2b(acc[i][j][1] + bn);
        pk.z = f2b(acc[i][j][2] + bn);
        pk.w = f2b(acc[i][j][3] + bn);
        *(ushort4*)(VF + (size_t)bt * DIM * SEQ +
                    (size_t)((d >> 4) * 64 + (t0 >> 5)) * 512 +
                    ((((t0 & 31) >> 3) << 4) | (d & 15)) * 8 + (t0 & 7)) = pk;
      }
    }
  }
}

// ---- K2: S^T = K Q^T, 256t x 256s tiles; exp epilogue -> ScF + rowsum -----
__global__ __launch_bounds__(512, 2) void scores_kernel(
    const unsigned short* __restrict__ QF, const unsigned short* __restrict__ KF,
    unsigned short* __restrict__ ScF, float* __restrict__ rowsum)
{
  __shared__ char lds[131072];   // 4 x 32 KB slots
  const int b = blockIdx.z, x = blockIdx.x, y = blockIdx.y;
  const int lane = threadIdx.x & 63, w = threadIdx.x >> 6;
  const int wm = w & 1, wn = w >> 1;             // WM=2, WN=4
  floatx4 acc[8][4] = {};
  fgemm_8p<16, 16, 2, 4, 1, 2, 16>((const char*)KF + (size_t)b * 2097152, y * 16, 16,
                                   (const char*)QF + (size_t)b * 2097152, x * 16, 16,
                                   lds, acc);

  unsigned short* S = ScF + (size_t)b * SEQ * SEQ;
  const float scale = 0.044194173824159216f;  // 1/sqrt(512)
  const int tbase = y * 256 + wm * 128;
  const int sbase = x * 256 + wn * 64;
  float colsum[4] = {0.f, 0.f, 0.f, 0.f};
#pragma unroll
  for (int i = 0; i < 8; ++i) {
    const int t0 = tbase + i * 16 + (lane >> 4) * 4;
#pragma unroll
    for (int j = 0; j < 4; ++j) {
      const int s = sbase + j * 16 + (lane & 15);
      float e0 = __expf(acc[i][j][0] * scale);
      float e1 = __expf(acc[i][j][1] * scale);
      float e2 = __expf(acc[i][j][2] * scale);
      float e3 = __expf(acc[i][j][3] * scale);
      colsum[j] += (e0 + e1) + (e2 + e3);
      ushort4 pk;
      pk.x = f2b(e0); pk.y = f2b(e1); pk.z = f2b(e2); pk.w = f2b(e3);
      *(ushort4*)(S + (size_t)((s >> 4) * 64 + (t0 >> 5)) * 512 +
                  ((((t0 & 31) >> 3) << 4) | (s & 15)) * 8 + (t0 & 7)) = pk;
    }
  }
#pragma unroll
  for (int j = 0; j < 4; ++j) {
    colsum[j] += __shfl_xor(colsum[j], 16, 64);
    colsum[j] += __shfl_xor(colsum[j], 32, 64);
  }
  if (lane < 16) {
#pragma unroll
    for (int j = 0; j < 4; ++j)
      atomicAdd(rowsum + b * SEQ + sbase + j * 16 + lane, colsum[j]);
  }
}

// ---- K3: out[s][d] = (ScF . VF) / rowsum[s]; 128x128 tile, BK=64 ----------
__global__ __launch_bounds__(512, 2) void pv_kernel(
    const unsigned short* __restrict__ ScF, const unsigned short* __restrict__ VF,
    const float* __restrict__ rowsum, float* __restrict__ out)
{
  __shared__ char lds[131072];   // 4 x 32 KB slots
  const int b = blockIdx.z, x = blockIdx.x, y = blockIdx.y;
  const int lane = threadIdx.x & 63, w = threadIdx.x >> 6;
  const int wm = w & 1, wn = w >> 1;             // WM=2, WN=4
  floatx4 acc[4][2] = {};
  fgemm_8p<8, 8, 2, 4, 2, 1, 32>((const char*)ScF + (size_t)b * 8388608, x * 8, 64,
                                 (const char*)VF + (size_t)b * 2097152, y * 8, 64,
                                 lds, acc);

  const int mbase = x * 128 + wm * 64;
  const int dbase = y * 128 + wn * 32;
#pragma unroll
  for (int i = 0; i < 4; ++i) {
    const int m0 = mbase + i * 16 + (lane >> 4) * 4;
    const float4 rs = *(const float4*)(rowsum + b * SEQ + m0);
    const float inv0 = 1.f / rs.x, inv1 = 1.f / rs.y, inv2 = 1.f / rs.z, inv3 = 1.f / rs.w;
#pragma unroll
    for (int j = 0; j < 2; ++j) {
      const int d = dbase + j * 16 + (lane & 15);
      float* o = out + ((size_t)b * SEQ + m0) * DIM + d;
      o[0 * DIM] = acc[i][j][0] * inv0;
      o[1 * DIM] = acc[i][j][1] * inv1;
      o[2 * DIM] = acc[i][j][2] * inv2;
      o[3 * DIM] = acc[i][j][3] * inv3;
    }
  }
}

extern "C" void kernel_launch(void* const* d_in, const int* in_sizes, int n_in,
                              void* d_out, int out_size, void* d_ws, size_t ws_size,
                              hipStream_t stream) {
  const float* X  = (const float*)d_in[0];
  const float* Wq = (const float*)d_in[1];
  const float* bq = (const float*)d_in[2];
  const float* Wk = (const float*)d_in[3];
  const float* bk = (const float*)d_in[4];
  const float* Wv = (const float*)d_in[5];
  const float* bv = (const float*)d_in[6];
  float* out = (float*)d_out;
  char* ws = (char*)d_ws;

  // workspace layout (bytes)
  short8* XbF = (short8*)(ws + 0);                    //  8 MB   (rows=b*S+s, K=512)
  short8* WF  = (short8*)(ws + 8388608);              //  1.5 MB (rows=n, K=512, x3)
  char*   QF  = ws + 9961472;                         //  8 MB   (rows=s, K=d)
  char*   KF  = ws + 18350080;                        //  8 MB   (rows=s, K=d)
  char*   VF  = ws + 26738688;                        //  8 MB   (rows=d, K=t, per b)
  char*   ScF = ws + 35127296;                        // 32 MB   (rows=s, K=t, per b)
  float*  rowsum = (float*)(ws + 68681728);           // 32 KB

  setup_kernel<<<dim3(2048), 256, 0, stream>>>(X, Wq, Wk, Wv, XbF, WF, rowsum);
  qkv_kernel<<<dim3(64, 1, 3), 512, 0, stream>>>(
      XbF, WF, bq, bk, bv,
      (unsigned short*)QF, (unsigned short*)KF, (unsigned short*)VF);
  scores_kernel<<<dim3(8, 8, 4), 512, 0, stream>>>(
      (const unsigned short*)QF, (const unsigned short*)KF,
      (unsigned short*)ScF, rowsum);
  pv_kernel<<<dim3(16, 4, 4), 512, 0, stream>>>(
      (const unsigned short*)ScF, (const unsigned short*)VF, rowsum, out);
}